// Round 6
// baseline (36.207 us; speedup 1.0000x reference)
//
#include <hip/hip_runtime.h>
#include <math.h>

#define NYX 192
#define NNODE 193
#define L_NODES (NNODE*NNODE)     /* 37249 */
#define NPAIR 11
#define NB 2
#define NCH 12
#define NGRP (NPAIR*NB)           /* 22 reduction groups */
#define NBLK 49                   /* row-blocks: ceil(193 rows / 4 rows-per-block) */
#define TOTAL_BLOCKS (NBLK*NB*NPAIR)  /* 1078 */
#define LN2f 0.69314718055994530942f

/* ws layout:
   [0, 1408)      float acc[NGRP][16]   group accumulators, 64B-padded per group
   [1408, 1412)   unsigned ticket                                               */
#define ACC_STRIDE 16

__global__ __launch_bounds__(256) void sdice_fused(const float* __restrict__ pred,
                                                   const float* __restrict__ labels,
                                                   const float* __restrict__ area,
                                                   float* __restrict__ acc,
                                                   unsigned* __restrict__ ticket,
                                                   float* __restrict__ out)
{
    const int pair = blockIdx.z;
    const int b    = blockIdx.y;
    const int lane = threadIdx.x & 63;   /* one wave == one node row; lanes 0..47 active */
    const int wrow = threadIdx.x >> 6;
    const int j    = blockIdx.x * 4 + wrow;   /* node row (guard j<193) */
    const int t    = lane;                    /* x-group: nodes 4t..4t+3 */

    __shared__ float areas[256];
    __shared__ float sred[4][4];
    __shared__ int   isLast;
    __shared__ float gs[NGRP][4];
    areas[threadIdx.x] = area[threadIdx.x];
    __syncthreads();

    float num = 0.f, den = 0.f, bces = 0.f, cnt = 0.f;
    const bool act = (j < NNODE) && (t < 48);

    if (act) {
        /* windows over x = 4t-1 .. 4t+4 for each (c,ky)=cr */
        float sig6[4][6], bcv6[4][6];
        unsigned w5[4];

        const int  y0 = (j >= 1) ? (j - 1) : 0;          /* clamped rows, loads always valid */
        const int  y1 = (j <= NYX - 1) ? j : (NYX - 1);
        const bool m0 = (j >= 1);
        const bool m1 = (j <= NYX - 1);
        const int  xo = t * 4;

        #pragma unroll
        for (int c = 0; c < 2; ++c) {
            const size_t base = (size_t)(b * NCH + pair + c) * (NYX * NYX);
            #pragma unroll
            for (int r = 0; r < 2; ++r) {
                const int  cr = c * 2 + r;
                const int  yy = r ? y1 : y0;
                const bool mm = r ? m1 : m0;
                const float4 p4 = *reinterpret_cast<const float4*>(pred   + base + (size_t)yy * NYX + xo);
                const float4 l4 = *reinterpret_cast<const float4*>(labels + base + (size_t)yy * NYX + xo);
                const float pe[4] = {p4.x, p4.y, p4.z, p4.w};
                const float le[4] = {l4.x, l4.y, l4.z, l4.w};
                unsigned bits = 0;
                #pragma unroll
                for (int e = 0; e < 4; ++e) {
                    const float pv = mm ? pe[e] : 0.f;   /* row-OOB -> padded zeros */
                    const float lv = mm ? le[e] : 0.f;
                    bits |= ((unsigned)lv) << e;
                    const float s = __builtin_amdgcn_rcpf(1.f + __expf(-pv));
                    sig6[cr][e + 1] = mm ? s : 0.f;      /* pad AFTER sigmoid -> 0 */
                    bcv6[cr][e + 1] = fmaxf(pv, 0.f) - pv * lv + __logf(1.f + __expf(-fabsf(pv)));
                }
                w5[cr] = bits << 1;
                sig6[cr][5] = 0.f;      /* x = 4t+4 slot, only used by node 192 (x OOB) */
                bcv6[cr][5] = LN2f;
            }
        }

        /* x = 4t-1 halo from lane-1 (wave is row-aligned; lane 0 is the real x=0 border) */
        #pragma unroll
        for (int cr = 0; cr < 4; ++cr) {
            const float    sw = __shfl_up(sig6[cr][4], 1);
            const float    bw = __shfl_up(bcv6[cr][4], 1);
            const unsigned ww = (unsigned)__shfl_up((int)w5[cr], 1);
            sig6[cr][0] = (t == 0) ? 0.f  : sw;
            bcv6[cr][0] = (t == 0) ? LN2f : bw;
            w5[cr]     |= (t == 0) ? 0u   : ((ww >> 4) & 1u);
        }

        /* nodes ix = 4t+i ; i=4 (ix=192) only on lane 47 */
        #pragma unroll
        for (int i = 0; i < 5; ++i) {
            if (i < 4 || t == 47) {
                unsigned byte = 0;
                float d2 = 0.f, bsum = 0.f;
                #pragma unroll
                for (int cr = 0; cr < 4; ++cr) {
                    const unsigned bp = (w5[cr] >> i) & 1u;
                    const unsigned bc = (w5[cr] >> (i + 1)) & 1u;
                    byte |= (bp << (2 * cr)) | (bc << (2 * cr + 1));
                    const float dp = sig6[cr][i]     - (float)bp;
                    const float dc = sig6[cr][i + 1] - (float)bc;
                    d2   += dp * dp + dc * dc;
                    bsum += bcv6[cr][i] + bcv6[cr][i + 1];
                }
                const float w  = 1.f - sqrtf(d2) * (1.f / 16.f);
                const float la = areas[byte];
                num += w * la;
                den += la;
                const bool msk = (byte == 0u) || (byte == 255u);
                cnt  += msk ? 1.f : 0.f;
                bces += msk ? bsum : 0.f;
            }
        }
    }

    /* wave shuffle reduce + cross-wave LDS */
    #pragma unroll
    for (int off = 32; off > 0; off >>= 1) {
        num  += __shfl_down(num, off);
        den  += __shfl_down(den, off);
        bces += __shfl_down(bces, off);
        cnt  += __shfl_down(cnt, off);
    }
    if (lane == 0) { sred[wrow][0] = num; sred[wrow][1] = den; sred[wrow][2] = bces; sred[wrow][3] = cnt; }
    __syncthreads();

    /* leader: group-accumulator atomics (64B-padded line per group), then ticket */
    if (threadIdx.x == 0) {
        float n = 0, d = 0, bc = 0, ct = 0;
        #pragma unroll
        for (int w = 0; w < 4; ++w) { n += sred[w][0]; d += sred[w][1]; bc += sred[w][2]; ct += sred[w][3]; }
        float* g = acc + (size_t)(pair * NB + b) * ACC_STRIDE;
        atomicAdd(g + 0, n);
        atomicAdd(g + 1, d);
        atomicAdd(g + 2, bc);
        atomicAdd(g + 3, ct);
        __threadfence();                       /* acc RMWs complete before ticket */
        const unsigned tk = atomicAdd(ticket, 1u);
        isLast = (tk == TOTAL_BLOCKS - 1);
    }
    __syncthreads();

    if (isLast) {
        __threadfence();
        if (threadIdx.x < NGRP * 4) {          /* 88 parallel coherent reads */
            const int g = threadIdx.x >> 2;
            const int v = threadIdx.x & 3;
            gs[g][v] = atomicAdd(acc + (size_t)g * ACC_STRIDE + v, 0.0f);
        }
        __syncthreads();
        if (threadIdx.x == 0) {
            const float a1 = areas[1];   /* pred_byte == 1 everywhere (strict '>' in fori_loop) */
            float dice_sum = 0.f, vol_sum = 0.f;
            for (int bb = 0; bb < NB; ++bb) {
                float numb = 0.f, denb = 0.f, volb = 0.f;
                for (int p = 0; p < NPAIR; ++p) {
                    const int g = p * NB + bb;
                    numb += 2.0f * gs[g][0];
                    denb += gs[g][1] + (float)L_NODES * a1;
                    volb += gs[g][2] / (8.0f * gs[g][3]);
                }
                dice_sum += 1.0f - (numb + 0.001f) / (denb + 0.001f);
                vol_sum  += volb;
            }
            out[0] = dice_sum / (float)NB + vol_sum / (float)NB;
        }
    }
}

extern "C" void kernel_launch(void* const* d_in, const int* in_sizes, int n_in,
                              void* d_out, int out_size, void* d_ws, size_t ws_size,
                              hipStream_t stream) {
    const float* pred   = (const float*)d_in[0];
    const float* labels = (const float*)d_in[1];
    const float* area   = (const float*)d_in[2];
    float* out = (float*)d_out;
    char*  ws  = (char*)d_ws;

    float*    acc    = (float*)ws;
    unsigned* ticket = (unsigned*)(ws + NGRP * ACC_STRIDE * sizeof(float));

    /* zero accumulators + ticket each call -> deterministic across graph replays */
    hipMemsetAsync(ws, 0, NGRP * ACC_STRIDE * sizeof(float) + sizeof(unsigned), stream);

    dim3 grid(NBLK, NB, NPAIR);
    sdice_fused<<<grid, dim3(256), 0, stream>>>(pred, labels, area, acc, ticket, out);
}

// Round 7
// 19.229 us; speedup vs baseline: 1.8829x; 1.8829x over previous
//
#include <hip/hip_runtime.h>
#include <math.h>

#define NYX 192
#define NNODE 193
#define L_NODES (NNODE*NNODE)     /* 37249 */
#define NPAIR 11
#define NB 2
#define NCH 12
#define NZ 3                      /* channel-groups: z=0 pairs 0-3, z=1 pairs 4-7, z=2 pairs 8-10 */
#define NGRP (NZ*NB)              /* 6 partial groups */
#define NBLK 49                   /* row-blocks: ceil(193/4) */
#define RECF 12                   /* floats per partial record: num,den,bce[4],cnt[4],pad2 */
#define LN2f 0.69314718055994530942f

/* ws: float partials[NGRP*NBLK*RECF]  (6*49*12*4 = 14112 B) */

__global__ __launch_bounds__(256) void sdice_node(const float* __restrict__ pred,
                                                  const float* __restrict__ labels,
                                                  const float* __restrict__ area,
                                                  float* __restrict__ partials)
{
    const int z    = blockIdx.z;             /* channel group */
    const int b    = blockIdx.y;
    const int lane = threadIdx.x & 63;       /* one wave == one node row; lanes 0..47 active */
    const int wrow = threadIdx.x >> 6;
    const int j    = blockIdx.x * 4 + wrow;  /* node row (guard j<193) */
    const int t    = lane;                   /* x-group: nodes 4t..4t+3 */
    const int np   = (z == 2) ? 3 : 4;       /* pairs in this group */
    const int nch  = np + 1;
    const int c0   = z * 4;

    __shared__ float areas[256];
    __shared__ float sred[4][10];
    areas[threadIdx.x] = area[threadIdx.x];
    __syncthreads();

    float numA = 0.f, denA = 0.f;
    float bceA[4] = {0.f, 0.f, 0.f, 0.f};
    float cntA[4] = {0.f, 0.f, 0.f, 0.f};

    const bool act = (j < NNODE) && (t < 48);

    if (act) {
        const int  y0 = (j >= 1) ? (j - 1) : 0;        /* clamped rows -> loads always valid */
        const int  y1 = (j <= NYX - 1) ? j : (NYX - 1);
        const int  xo = t * 4;

        float    sigP[2][6], bcvP[2][6], sigC[2][6], bcvC[2][6];
        unsigned w5P[2], w5C[2];

        for (int cc = 0; cc < nch; ++cc) {             /* wave-uniform runtime loop */
            const int ch = c0 + cc;
            const size_t base = (size_t)(b * NCH + ch) * (NYX * NYX);

            #pragma unroll
            for (int r = 0; r < 2; ++r) {
                const int  yy = r ? y1 : y0;
                const bool mm = r ? (j <= NYX - 1) : (j >= 1);
                const float4 p4 = *reinterpret_cast<const float4*>(pred   + base + (size_t)yy * NYX + xo);
                const float4 l4 = *reinterpret_cast<const float4*>(labels + base + (size_t)yy * NYX + xo);
                const float pe[4] = {p4.x, p4.y, p4.z, p4.w};
                const float le[4] = {l4.x, l4.y, l4.z, l4.w};
                unsigned bits = 0;
                #pragma unroll
                for (int e = 0; e < 4; ++e) {
                    const float pv = mm ? pe[e] : 0.f;     /* row-OOB -> padded zeros */
                    const float lv = mm ? le[e] : 0.f;
                    bits |= ((unsigned)lv) << e;
                    const float s = __builtin_amdgcn_rcpf(1.f + __expf(-pv));
                    sigC[r][e + 1] = mm ? s : 0.f;         /* pad AFTER sigmoid -> 0 */
                    bcvC[r][e + 1] = fmaxf(pv, 0.f) - pv * lv + __logf(1.f + __expf(-fabsf(pv)));
                }
                w5C[r] = bits << 1;
                sigC[r][5] = 0.f;        /* x = 4t+4 slot, used only by node 192 (x OOB) */
                bcvC[r][5] = LN2f;

                /* x = 4t-1 halo from lane-1 (lane 0 is the real x=0 border) */
                const float    sw = __shfl_up(sigC[r][4], 1);
                const float    bw = __shfl_up(bcvC[r][4], 1);
                const unsigned ww = (unsigned)__shfl_up((int)w5C[r], 1);
                sigC[r][0] = (t == 0) ? 0.f  : sw;
                bcvC[r][0] = (t == 0) ? LN2f : bw;
                w5C[r]    |= (t == 0) ? 0u   : ((ww >> 4) & 1u);
            }

            if (cc > 0) {
                const int pp = cc - 1;                   /* pair index within group */
                float pnum = 0.f, pden = 0.f, pbce = 0.f, pcnt = 0.f;
                #pragma unroll
                for (int i = 0; i < 5; ++i) {
                    if (i < 4 || t == 47) {              /* node ix=192 only on lane 47 */
                        const unsigned b0 = (w5P[0] >> i) & 1u, b1 = (w5P[0] >> (i + 1)) & 1u;
                        const unsigned b2 = (w5P[1] >> i) & 1u, b3 = (w5P[1] >> (i + 1)) & 1u;
                        const unsigned b4 = (w5C[0] >> i) & 1u, b5 = (w5C[0] >> (i + 1)) & 1u;
                        const unsigned b6 = (w5C[1] >> i) & 1u, b7 = (w5C[1] >> (i + 1)) & 1u;
                        const unsigned byte = b0 | (b1 << 1) | (b2 << 2) | (b3 << 3)
                                            | (b4 << 4) | (b5 << 5) | (b6 << 6) | (b7 << 7);
                        float d2 = 0.f;
                        {
                            const float e0 = sigP[0][i]     - (float)b0;
                            const float e1 = sigP[0][i + 1] - (float)b1;
                            const float e2 = sigP[1][i]     - (float)b2;
                            const float e3 = sigP[1][i + 1] - (float)b3;
                            const float e4 = sigC[0][i]     - (float)b4;
                            const float e5 = sigC[0][i + 1] - (float)b5;
                            const float e6 = sigC[1][i]     - (float)b6;
                            const float e7 = sigC[1][i + 1] - (float)b7;
                            d2 = ((e0*e0 + e1*e1) + (e2*e2 + e3*e3)) + ((e4*e4 + e5*e5) + (e6*e6 + e7*e7));
                        }
                        const float w  = 1.f - sqrtf(d2) * (1.f / 16.f);
                        const float la = areas[byte];
                        pnum += w * la;
                        pden += la;
                        const bool msk = (byte == 0u) || (byte == 255u);
                        if (msk) {
                            pcnt += 1.f;
                            pbce += ((bcvP[0][i] + bcvP[0][i+1]) + (bcvP[1][i] + bcvP[1][i+1]))
                                  + ((bcvC[0][i] + bcvC[0][i+1]) + (bcvC[1][i] + bcvC[1][i+1]));
                        }
                    }
                }
                numA += pnum; denA += pden;
                bceA[pp] += pbce; cntA[pp] += pcnt;      /* pp static per unrolled...: cc runtime */
            }

            /* prev <- cur */
            #pragma unroll
            for (int r = 0; r < 2; ++r) {
                w5P[r] = w5C[r];
                #pragma unroll
                for (int q = 0; q < 6; ++q) { sigP[r][q] = sigC[r][q]; bcvP[r][q] = bcvC[r][q]; }
            }
        }
    }

    /* NOTE: bceA/cntA indexed by runtime pp -> force into scratch-free form via small fixed array
       (4 elems; compiler keeps in VGPRs when loop is short; acceptable either way at this size) */

    /* wave shuffle reduce of 10 values */
    float v[10] = {numA, denA, bceA[0], bceA[1], bceA[2], bceA[3], cntA[0], cntA[1], cntA[2], cntA[3]};
    #pragma unroll
    for (int off = 32; off > 0; off >>= 1) {
        #pragma unroll
        for (int q = 0; q < 10; ++q) v[q] += __shfl_down(v[q], off);
    }
    if (lane == 0) {
        #pragma unroll
        for (int q = 0; q < 10; ++q) sred[wrow][q] = v[q];
    }
    __syncthreads();
    if (threadIdx.x == 0) {
        float s[10];
        #pragma unroll
        for (int q = 0; q < 10; ++q)
            s[q] = ((sred[0][q] + sred[1][q]) + (sred[2][q] + sred[3][q]));
        float* rec = partials + (size_t)((z * NB + b) * NBLK + blockIdx.x) * RECF;
        #pragma unroll
        for (int q = 0; q < 10; ++q) rec[q] = s[q];
        rec[10] = 0.f; rec[11] = 0.f;
    }
}

__global__ __launch_bounds__(384) void sdice_final(const float* __restrict__ partials,
                                                   const float* __restrict__ area,
                                                   float* __restrict__ out)
{
    __shared__ float gs[NGRP][10];
    const int g    = threadIdx.x >> 6;      /* 6 waves, one per (z,b) group: g = z*NB+b */
    const int lane = threadIdx.x & 63;

    float v[10];
    #pragma unroll
    for (int q = 0; q < 10; ++q) v[q] = 0.f;
    if (lane < NBLK) {
        const float* rec = partials + (size_t)(g * NBLK + lane) * RECF;
        #pragma unroll
        for (int q = 0; q < 10; ++q) v[q] = rec[q];
    }
    #pragma unroll
    for (int off = 32; off > 0; off >>= 1) {
        #pragma unroll
        for (int q = 0; q < 10; ++q) v[q] += __shfl_down(v[q], off);
    }
    if (lane == 0) {
        #pragma unroll
        for (int q = 0; q < 10; ++q) gs[g][q] = v[q];
    }
    __syncthreads();

    if (threadIdx.x == 0) {
        const float a1 = area[1];   /* pred_byte == 1 everywhere (strict '>' in fori_loop) */
        float dice_sum = 0.f, vol_sum = 0.f;
        for (int b = 0; b < NB; ++b) {
            float numb = 0.f, denb = 0.f, volb = 0.f;
            for (int z = 0; z < NZ; ++z) {
                const int g2 = z * NB + b;
                const int np = (z == 2) ? 3 : 4;
                numb += 2.0f * gs[g2][0];
                denb += gs[g2][1];
                for (int pp = 0; pp < np; ++pp)
                    volb += gs[g2][2 + pp] / (8.0f * gs[g2][6 + pp]);
            }
            denb += (float)NPAIR * (float)L_NODES * a1;
            dice_sum += 1.0f - (numb + 0.001f) / (denb + 0.001f);
            vol_sum  += volb;
        }
        out[0] = dice_sum / (float)NB + vol_sum / (float)NB;
    }
}

extern "C" void kernel_launch(void* const* d_in, const int* in_sizes, int n_in,
                              void* d_out, int out_size, void* d_ws, size_t ws_size,
                              hipStream_t stream) {
    const float* pred   = (const float*)d_in[0];
    const float* labels = (const float*)d_in[1];
    const float* area   = (const float*)d_in[2];
    float* out  = (float*)d_out;
    float* part = (float*)d_ws;

    dim3 grid(NBLK, NB, NZ);
    sdice_node<<<grid, dim3(256), 0, stream>>>(pred, labels, area, part);
    sdice_final<<<1, 384, 0, stream>>>(part, area, out);
}